// Round 1
// 248.179 us; speedup vs baseline: 1.0679x; 1.0679x over previous
//
#include <hip/hip_runtime.h>
#include <hip/hip_bf16.h>
#include <cstdint>
#include <cstddef>

#define B_ 4
#define S_ 2048
#define E_ 768
#define H_ 12
#define D_ 64

typedef __bf16 bf16x8 __attribute__((ext_vector_type(8)));
typedef float f32x4 __attribute__((ext_vector_type(4)));

__constant__ float c_slopes[12] = {
    0.6299605249f, 0.396850263f, 0.25f, 0.1574901312f,
    0.0992125657f, 0.0625f, 0.0393725328f, 0.0248031414f,
    0.015625f, 0.0098431332f, 0.0062007854f, 0.00390625f};

__device__ __forceinline__ unsigned short f2bf_u(float f) {
    unsigned u = __builtin_bit_cast(unsigned, f);
    u += 0x7fffu + ((u >> 16) & 1u);   // round-to-nearest-even
    return (unsigned short)(u >> 16);
}
__device__ __forceinline__ __bf16 f2bf(float f) {
    unsigned short s = f2bf_u(f);
    return __builtin_bit_cast(__bf16, s);
}

// async global->LDS, 16B per lane, dest = wave-uniform base + lane*16
__device__ __forceinline__ void gload_lds16(const void* g, void* l) {
    __builtin_amdgcn_global_load_lds(
        (const __attribute__((address_space(1))) unsigned int*)g,
        (__attribute__((address_space(3))) unsigned int*)l, 16, 0, 0);
}

// ---------------------------------------------------------------------------
// prep: x fp32 -> bf16 (6.29M elems)
// ---------------------------------------------------------------------------
__global__ __launch_bounds__(256) void cvt_x(const float* __restrict__ src,
                                             __bf16* __restrict__ dst) {
    int i = (blockIdx.x * 256 + threadIdx.x) * 4;
    float4 v = *(const float4*)(src + i);
    ushort4 o;
    o.x = f2bf_u(v.x); o.y = f2bf_u(v.y); o.z = f2bf_u(v.z); o.w = f2bf_u(v.w);
    *(ushort4*)((unsigned short*)dst + i) = o;
}

// ---------------------------------------------------------------------------
// prep: W fp32 [k][n] -> Wt bf16 [n][k]; z picks which of 4 matrices
// ---------------------------------------------------------------------------
__global__ __launch_bounds__(256) void wtrans(const float* __restrict__ W0,
                                              const float* __restrict__ W1,
                                              const float* __restrict__ W2,
                                              const float* __restrict__ W3,
                                              __bf16* __restrict__ Wt) {
    const float* W = blockIdx.z == 0 ? W0 : blockIdx.z == 1 ? W1
                   : blockIdx.z == 2 ? W2 : W3;
    __bf16* out = Wt + (size_t)blockIdx.z * E_ * E_;
    __shared__ alignas(16) __bf16 ts[64 * 72];
    const int t = threadIdx.x;
    const int k0 = blockIdx.y * 64, n0 = blockIdx.x * 64;
#pragma unroll
    for (int i = 0; i < 4; i++) {
        int idx = i * 256 + t;          // 1024 float4 chunks
        int row = idx >> 4, c4 = idx & 15;
        float4 v = *(const float4*)(W + (size_t)(k0 + row) * E_ + n0 + c4 * 4);
        ts[(c4 * 4 + 0) * 72 + row] = f2bf(v.x);
        ts[(c4 * 4 + 1) * 72 + row] = f2bf(v.y);
        ts[(c4 * 4 + 2) * 72 + row] = f2bf(v.z);
        ts[(c4 * 4 + 3) * 72 + row] = f2bf(v.w);
    }
    __syncthreads();
#pragma unroll
    for (int i = 0; i < 2; i++) {
        int idx = i * 256 + t;          // 512 chunks of 8 bf16
        int r = idx >> 3, c8 = idx & 7;
        *(uint4*)((unsigned short*)out + (size_t)(n0 + r) * E_ + k0 + c8 * 8) =
            *(const uint4*)((const unsigned short*)ts + r * 72 + c8 * 8);
    }
}

// ---------------------------------------------------------------------------
// GEMM: out = A(8192x768 bf16) @ Wt^T + bias. Wt is [n][k] bf16.
// R7 single-BK32 m97-style staging (best measured). Bias prefetched into
// registers before the K-loop (scattered 4B loads were latency-exposed in
// the epilogue). z=2 -> V written transposed [bh][d][s].
// ---------------------------------------------------------------------------
template <bool PERM>
__global__ __launch_bounds__(256) void gemm_bf(
    const __bf16* __restrict__ A, const __bf16* __restrict__ WtAll,
    const float* __restrict__ b0, const float* __restrict__ b1,
    const float* __restrict__ b2,
    float* __restrict__ outF, __bf16* __restrict__ outB_base) {
    constexpr int Kd = E_, N = E_;
    __shared__ alignas(16) __bf16 Asm[128 * 32];   // 64B rows, no pad (m97)
    __shared__ alignas(16) __bf16 Bsm[128 * 32];

    const int t = threadIdx.x;
    const int w = t >> 6, lane = t & 63;
    const int qm = lane & 15, quad = lane >> 4;
    const int m0 = blockIdx.y * 128, n0 = blockIdx.x * 128;
    const int wm = (w >> 1) * 64, wn = (w & 1) * 64;
    const int z = blockIdx.z;
    const __bf16* Wt = WtAll + (size_t)z * Kd * N;
    const float* bias = PERM ? (z == 0 ? b0 : z == 1 ? b1 : b2) : b0;
    __bf16* outB = PERM ? outB_base + (size_t)z * ((size_t)B_ * S_ * E_) : nullptr;

    // bias prefetch: 4 scattered loads issued before the K-loop
    float bvv[4];
#pragma unroll
    for (int j = 0; j < 4; j++) bvv[j] = bias[n0 + wn + j * 16 + qm];

    // staging: 1024B wave-chunk = 16 rows x 64B; wave w owns chunks {2w,2w+1}
    const int crow = lane >> 2;       // row within chunk
    const int ccol = lane & 3;        // 16B quarter within row

    f32x4 acc[4][4] = {};

    for (int k0 = 0; k0 < Kd; k0 += 32) {
#pragma unroll
        for (int cc = 0; cc < 2; cc++) {
            int chunk = w * 2 + cc;
            int row = chunk * 16 + crow;
            gload_lds16((const unsigned short*)A + (size_t)(m0 + row) * Kd + k0 + ccol * 8,
                        Asm + chunk * 512);
            gload_lds16((const unsigned short*)Wt + (size_t)(n0 + row) * Kd + k0 + ccol * 8,
                        Bsm + chunk * 512);
        }
        __syncthreads();

        bf16x8 af[4], bg[4];
#pragma unroll
        for (int i = 0; i < 4; i++)
            af[i] = *(const bf16x8*)(Asm + (wm + i * 16 + qm) * 32 + quad * 8);
#pragma unroll
        for (int j = 0; j < 4; j++)
            bg[j] = *(const bf16x8*)(Bsm + (wn + j * 16 + qm) * 32 + quad * 8);
#pragma unroll
        for (int i = 0; i < 4; i++)
#pragma unroll
            for (int j = 0; j < 4; j++)
                acc[i][j] = __builtin_amdgcn_mfma_f32_16x16x32_bf16(
                    af[i], bg[j], acc[i][j], 0, 0, 0);
        __syncthreads();
    }

    // epilogue: C/D layout col=lane&15, row=quad*4+reg
#pragma unroll
    for (int i = 0; i < 4; i++) {
#pragma unroll
        for (int j = 0; j < 4; j++) {
            int col = n0 + wn + j * 16 + qm;
            int rowb = m0 + wm + i * 16 + quad * 4;
            if (PERM && z == 2) {
                // V -> Vt [bh][d][s]: rows r are consecutive s, pack 4 bf16
                int b = rowb >> 11, s = rowb & (S_ - 1);
                int h = col >> 6, d = col & (D_ - 1);
                unsigned short pk4[4];
#pragma unroll
                for (int r = 0; r < 4; r++) pk4[r] = f2bf_u(acc[i][j][r] + bvv[j]);
                uint2 pv;
                pv.x = (unsigned)pk4[0] | ((unsigned)pk4[1] << 16);
                pv.y = (unsigned)pk4[2] | ((unsigned)pk4[3] << 16);
                *(uint2*)((unsigned short*)outB +
                          ((size_t)(b * H_ + h) * D_ + d) * S_ + s) = pv;
            } else {
#pragma unroll
                for (int r = 0; r < 4; r++) {
                    int row = rowb + r;
                    float val = acc[i][j][r] + bvv[j];
                    if (PERM) {
                        int b = row >> 11, s = row & (S_ - 1);
                        int h = col >> 6, d = col & (D_ - 1);
                        outB[(((size_t)(b * H_ + h)) * S_ + s) * D_ + d] = f2bf(val);
                    } else {
                        outF[(size_t)row * N + col] = val;
                    }
                }
            }
        }
    }
}

// ---------------------------------------------------------------------------
// Flash attention (S^T formulation, analytic-max softmax, causal + ALiBi).
// R11: (a) PAIRED q-tiles (x, 31-x) per block -> uniform 33 tile-computes
// per block (fixes the per-CU qt imbalance: old mapping put 6 same-qt blocks
// on each CU, critical CUs did 192 iters vs avg 99). K/V staged ONCE per kt
// and reused by both q-tiles. Grid (48,16): same-bh blocks land on one XCD
// (48%8==0) -> K/V L2-local (6 heads x 0.5MB per XCD).
// (b) XOR-swizzled K/V + P LDS (both-sides: pre-swizzled gload source
// quarter + same involution on reads). Kills the 8-way bank conflicts
// (8.9M conflict cycles/dispatch) on ak/bv/ap reads.
// ---------------------------------------------------------------------------
__global__ __launch_bounds__(256, 3) void attn_k(
    const __bf16* __restrict__ Q, const __bf16* __restrict__ K,
    const __bf16* __restrict__ Vt, __bf16* __restrict__ O) {
    __shared__ alignas(16) __bf16 Ksm[2][64 * 32];   // [dhalf][key][d%32] swz
    __shared__ alignas(16) __bf16 Vsm[2][64 * 32];   // [khalf][d][key%32] swz
    __shared__ alignas(16) __bf16 Psm[4 * 16 * 64];  // per-wave P, 128B rows swz

    const int t = threadIdx.x;
    const int w = t >> 6, lane = t & 63;
    const int qm = lane & 15, quad = lane >> 4;
    const int xp = blockIdx.y;                    // pair id 0..15
    const int qlo = xp, qhi = 31 - xp;            // (xp+1) + (32-xp) = 33 tiles
    const int bh = blockIdx.x;
    const float c2 = c_slopes[bh % H_] * 1.44269504f;     // slope * log2(e)
    const size_t base = (size_t)bh * S_ * D_;

    // Q B-fragments for both tiles (lane qm = q-col, contiguous over d)
    const int bbL = qlo * 64 + w * 16;
    const int bbH = qhi * 64 + w * 16;
    const __bf16* qpL = Q + base + (size_t)(bbL + qm) * D_ + quad * 8;
    const __bf16* qpH = Q + base + (size_t)(bbH + qm) * D_ + quad * 8;
    bf16x8 qL0 = *(const bf16x8*)qpL, qL1 = *(const bf16x8*)(qpL + 32);
    bf16x8 qH0 = *(const bf16x8*)qpH, qH1 = *(const bf16x8*)(qpH + 32);

    f32x4 oaccL[4] = {}, oaccH[4] = {};
    float lsumL = 0.f, lsumH = 0.f;
    char* Pb = (char*)Psm + w * 2048;             // this wave's 16x128B region

    // gload staging: wave w stages rows 16w..16w+15 of each array.
    // Source quarter pre-swizzled so LDS slot (r,c) holds global quarter
    // c ^ ((r&15)>>1 & 3)  (dest is HW-linear: base + lane*16).
    const int srow = lane >> 2;
    const int sq = (lane & 3) ^ ((lane >> 3) & 3);
    const unsigned short* Kg = (const unsigned short*)K + base +
                               (size_t)(16 * w + srow) * D_ + sq * 8;
    const unsigned short* Vg = (const unsigned short*)Vt + base +
                               (size_t)(16 * w + srow) * S_ + sq * 8;

    // swizzled read quarter (elems): global quarter `quad` of row (16i+qm)
    const int cq = (quad ^ ((qm >> 1) & 3)) * 8;
    // P swizzle: byte bits[6:4] ^= qm&7 within each 128B row
    const int pf = (qm & 7) << 4;

    int kt = 0;  // captured by tile lambda

    bf16x8 ak[4][2], bv[4][2];
    auto tilec = [&](const bf16x8& qf0, const bf16x8& qf1, f32x4* oacc,
                     float& lsum, int bb) {
        // S^T = K Q^T : lane (qm,quad) reg r holds S^T[key=16i+4quad+r][q=qm]
        f32x4 st[4];
#pragma unroll
        for (int i = 0; i < 4; i++) {
            f32x4 zz = {0.f, 0.f, 0.f, 0.f};
            zz = __builtin_amdgcn_mfma_f32_16x16x32_bf16(ak[i][0], qf0, zz, 0, 0, 0);
            zz = __builtin_amdgcn_mfma_f32_16x16x32_bf16(ak[i][1], qf1, zz, 0, 0, 0);
            st[i] = zz;
        }

        // analytic-max softmax: exponent = qk*scale*log2e - c2*key
        const int qi = bb + qm;
        const bool nomask = (kt * 64 + 63) <= bb;
        float ls = 0.f;
        unsigned pk[4][2];
#pragma unroll
        for (int i = 0; i < 4; i++) {
            float bi = -c2 * (float)(kt * 64 + 16 * i + 4 * quad);
            float p[4];
#pragma unroll
            for (int r = 0; r < 4; r++) {
                float tt = st[i][r] * 0.18033688f + (bi - c2 * (float)r);
                float pp = __builtin_amdgcn_exp2f(tt);
                if (!nomask) {
                    int key = kt * 64 + 16 * i + 4 * quad + r;
                    pp = (key > qi) ? 0.f : pp;
                }
                ls += pp;
                p[r] = pp;
            }
            // pack 4 fp32 -> 4 bf16 (round-half-up + v_perm byte select)
            unsigned u0 = __builtin_bit_cast(unsigned, p[0]) + 0x8000u;
            unsigned u1 = __builtin_bit_cast(unsigned, p[1]) + 0x8000u;
            unsigned u2 = __builtin_bit_cast(unsigned, p[2]) + 0x8000u;
            unsigned u3 = __builtin_bit_cast(unsigned, p[3]) + 0x8000u;
            pk[i][0] = __builtin_amdgcn_perm(u1, u0, 0x07060302u);
            pk[i][1] = __builtin_amdgcn_perm(u3, u2, 0x07060302u);
        }
        lsum += ls;

        // P[q=qm][key=16i+4quad+{0..3}] : b64 writes, swizzled within row
#pragma unroll
        for (int i = 0; i < 4; i++) {
            uint2 pv; pv.x = pk[i][0]; pv.y = pk[i][1];
            *(uint2*)(Pb + qm * 128 + ((32 * i + 8 * quad) ^ pf)) = pv;
        }

        // O += P V : A = P rows (b128, swizzled), B = V^T rows
        bf16x8 ap0 = *(const bf16x8*)(Pb + qm * 128 + ((quad * 16) ^ pf));
        bf16x8 ap1 = *(const bf16x8*)(Pb + qm * 128 + ((64 + quad * 16) ^ pf));
#pragma unroll
        for (int jd = 0; jd < 4; jd++) {
            oacc[jd] = __builtin_amdgcn_mfma_f32_16x16x32_bf16(
                ap0, bv[jd][0], oacc[jd], 0, 0, 0);
            oacc[jd] = __builtin_amdgcn_mfma_f32_16x16x32_bf16(
                ap1, bv[jd][1], oacc[jd], 0, 0, 0);
        }
    };

    for (kt = 0; kt <= qhi; kt++) {
        // async stage (shared by both q-tiles of the pair)
#pragma unroll
        for (int h = 0; h < 2; h++) {
            gload_lds16(Kg + (size_t)(kt * 64) * D_ + 32 * h, Ksm[h] + w * 512);
            gload_lds16(Vg + kt * 64 + 32 * h, Vsm[h] + w * 512);
        }
        __syncthreads();   // (compiler inserts vmcnt(0) drain before barrier)

        // K A-frags (m=key) and V B-frags (n=d), swizzled quarter reads
#pragma unroll
        for (int i = 0; i < 4; i++) {
            ak[i][0] = *(const bf16x8*)(Ksm[0] + (16 * i + qm) * 32 + cq);
            ak[i][1] = *(const bf16x8*)(Ksm[1] + (16 * i + qm) * 32 + cq);
        }
#pragma unroll
        for (int jd = 0; jd < 4; jd++) {
            bv[jd][0] = *(const bf16x8*)(Vsm[0] + (16 * jd + qm) * 32 + cq);
            bv[jd][1] = *(const bf16x8*)(Vsm[1] + (16 * jd + qm) * 32 + cq);
        }

        tilec(qH0, qH1, oaccH, lsumH, bbH);          // always
        if (kt <= qlo) tilec(qL0, qL1, oaccL, lsumL, bbL);  // block-uniform branch

        __syncthreads();   // protect buffers before next iteration's gloads
    }

    // epilogue: reduce l across quads (lane-local rows), divide, store
    auto epi = [&](f32x4* oacc, float lsum, int bb) {
        float lf = lsum;
        lf += __shfl_xor(lf, 16);
        lf += __shfl_xor(lf, 32);               // full l for q = bb+qm
#pragma unroll
        for (int r = 0; r < 4; r++) {
            float lr = __shfl(lf, 4 * quad + r);  // l for q = bb+4quad+r
            float inv = 1.0f / lr;
            int qrow = bb + 4 * quad + r;
#pragma unroll
            for (int jd = 0; jd < 4; jd++)
                O[base + (size_t)qrow * D_ + 16 * jd + qm] =
                    f2bf(oacc[jd][r] * inv);
        }
    };
    epi(oaccH, lsumH, bbH);
    epi(oaccL, lsumL, bbL);
}

// ---------------------------------------------------------------------------
extern "C" void kernel_launch(void* const* d_in, const int* in_sizes, int n_in,
                              void* d_out, int out_size, void* d_ws, size_t ws_size,
                              hipStream_t stream) {
    (void)in_sizes; (void)n_in; (void)out_size; (void)ws_size;
    const float* x  = (const float*)d_in[0];
    const float* Wq = (const float*)d_in[1];
    const float* bq = (const float*)d_in[2];
    const float* Wk = (const float*)d_in[3];
    const float* bk = (const float*)d_in[4];
    const float* Wv = (const float*)d_in[5];
    const float* bv = (const float*)d_in[6];
    const float* Wo = (const float*)d_in[7];
    const float* bo = (const float*)d_in[8];
    float* out = (float*)d_out;

    const size_t n = (size_t)B_ * H_ * S_ * D_;  // 6291456
    // ws layout (46 MB):
    //  [0,n):   xb (dead after QKV gemm)
    //  [n,2n):  Qb -> Ob (attn reads only its own Q rows before writing them)
    //  [2n,3n): Kb
    //  [3n,4n): Vtb  (V written transposed by QKV gemm epilogue, z=2)
    //  [4n,+):  Wt, 4 x 768*768 bf16
    __bf16* xb  = (__bf16*)d_ws;
    __bf16* Qb  = xb + n;
    __bf16* Kb  = xb + 2 * n;
    __bf16* Vtb = xb + 3 * n;
    __bf16* Wt  = xb + 4 * n;
    __bf16* Ob  = Qb;

    cvt_x<<<6144, 256, 0, stream>>>(x, xb);
    wtrans<<<dim3(12, 12, 4), 256, 0, stream>>>(Wq, Wk, Wv, Wo, Wt);
    gemm_bf<true><<<dim3(6, 64, 3), 256, 0, stream>>>(
        xb, Wt, bq, bk, bv, nullptr, Qb);
    attn_k<<<dim3(48, 16), 256, 0, stream>>>(Qb, Kb, Vtb, Ob);
    gemm_bf<false><<<dim3(6, 64, 1), 256, 0, stream>>>(
        Ob, Wt + 3 * (size_t)E_ * E_, bo, nullptr, nullptr, out, nullptr);
}